// Round 6
// baseline (252.895 us; speedup 1.0000x reference)
//
#include <hip/hip_runtime.h>
#include <math.h>

#define Bc 64
#define Nc 4
#define Ac 1024
#define Oc 128
#define Dc 256
#define Qc 256
#define Hc 128
#define BN (Bc*Nc)

using f4     = __attribute__((ext_vector_type(4))) float;
using f32x16 = __attribute__((ext_vector_type(16))) float;
using short8 = __attribute__((ext_vector_type(8))) short;
using us4    = __attribute__((ext_vector_type(4))) unsigned short;

__device__ inline float decode_t(const void* p) {
    int i = *(const int*)p;
    if (i >= 1 && i <= 1000000) return (float)i;
    return __int_as_float(i);
}

// round-to-nearest-even fp32 -> bf16
__device__ inline unsigned short bf16_rne(float x) {
    unsigned u = __builtin_bit_cast(unsigned, x);
    u += 0x7FFFu + ((u >> 16) & 1u);
    return (unsigned short)(u >> 16);
}

// split fp32 -> truncated bf16 hi + bf16(residual) lo.  x ~= hi + lo
__device__ inline void split_bf16(float x, unsigned short& hi, unsigned short& lo) {
    unsigned u = __builtin_bit_cast(unsigned, x);
    hi = (unsigned short)(u >> 16);
    float hif = __builtin_bit_cast(float, u & 0xFFFF0000u);
    float lof = x - hif;
    lo = (unsigned short)(__builtin_bit_cast(unsigned, lof) >> 16);
}

// ---------------------------------------------------------------------------
// prep_M: Mt[b][h][o] = sum_d W1[d][h] * obj[b][o][d]  (transposed, [h][o])
// bf16 hi/lo output. grid (4,2,64): 32h x 64o tile, 256 thr, double-buffered K.
// ---------------------------------------------------------------------------
__global__ __launch_bounds__(256) void prep_M_kernel(
    const float* __restrict__ obj, const float* __restrict__ W1,
    unsigned short* __restrict__ Mt_hi, unsigned short* __restrict__ Mt_lo)
{
    __shared__ float w_s[32][36];     // [k][h]
    __shared__ float obj_sT[32][68];  // [k][o]

    const int t  = threadIdx.x;
    const int tx = t & 15;    // o = o0 + tx*4 + j
    const int ty = t >> 4;    // h = h0 + ty*2 + i
    const int h0 = blockIdx.x * 32;
    const int o0 = blockIdx.y * 64;
    const int b  = blockIdx.z;
    const int r8 = t >> 3, c8 = t & 7;

    const float* objb = obj + ((size_t)b * Oc + o0) * Dc;

    float acc[2][4];
    #pragma unroll
    for (int i = 0; i < 2; i++)
        #pragma unroll
        for (int j = 0; j < 4; j++) acc[i][j] = 0.f;

    f4 wv  = *(const f4*)(W1 + (size_t)r8 * Hc + h0 + c8 * 4);
    f4 ov0 = *(const f4*)(objb + (size_t)r8 * Dc + c8 * 4);
    f4 ov1 = *(const f4*)(objb + (size_t)(r8 + 32) * Dc + c8 * 4);

    for (int ko = 0; ko < 8; ++ko) {
        *(f4*)&w_s[r8][c8 * 4] = wv;
        obj_sT[c8 * 4 + 0][r8] = ov0[0];
        obj_sT[c8 * 4 + 1][r8] = ov0[1];
        obj_sT[c8 * 4 + 2][r8] = ov0[2];
        obj_sT[c8 * 4 + 3][r8] = ov0[3];
        obj_sT[c8 * 4 + 0][r8 + 32] = ov1[0];
        obj_sT[c8 * 4 + 1][r8 + 32] = ov1[1];
        obj_sT[c8 * 4 + 2][r8 + 32] = ov1[2];
        obj_sT[c8 * 4 + 3][r8 + 32] = ov1[3];
        __syncthreads();
        if (ko < 7) {
            wv  = *(const f4*)(W1 + (size_t)((ko + 1) * 32 + r8) * Hc + h0 + c8 * 4);
            ov0 = *(const f4*)(objb + (size_t)r8 * Dc + (ko + 1) * 32 + c8 * 4);
            ov1 = *(const f4*)(objb + (size_t)(r8 + 32) * Dc + (ko + 1) * 32 + c8 * 4);
        }
        #pragma unroll 4
        for (int k = 0; k < 32; k++) {
            float a0 = w_s[k][ty * 2];
            float a1 = w_s[k][ty * 2 + 1];
            f4 bv = *(const f4*)&obj_sT[k][tx * 4];
            #pragma unroll
            for (int j = 0; j < 4; j++) {
                acc[0][j] += a0 * bv[j];
                acc[1][j] += a1 * bv[j];
            }
        }
        __syncthreads();
    }

    #pragma unroll
    for (int i = 0; i < 2; i++) {
        us4 hi, lo;
        #pragma unroll
        for (int j = 0; j < 4; j++) {
            unsigned short h16, l16;
            split_bf16(acc[i][j], h16, l16);
            hi[j] = h16; lo[j] = l16;
        }
        size_t ofs = ((size_t)b * Hc + h0 + ty * 2 + i) * Oc + o0 + tx * 4;
        *(us4*)(Mt_hi + ofs) = hi;
        *(us4*)(Mt_lo + ofs) = lo;
    }
}

// ---------------------------------------------------------------------------
// prep_qb: qb[bn,h] = q[bn,:] @ W1q + b1[h]
// ---------------------------------------------------------------------------
__global__ __launch_bounds__(512) void prep_qb_kernel(
    const float* __restrict__ q, const float* __restrict__ W1,
    const float* __restrict__ b1, float* __restrict__ qb)
{
    __shared__ float qs[256];
    __shared__ float red[4][128];
    const int t = threadIdx.x;
    const int bn = blockIdx.x;

    if (t < 256) qs[t] = q[bn * Qc + t];
    __syncthreads();

    const int h = t & 127, kq = t >> 7;
    float acc = 0.f;
    const float* w = W1 + (size_t)(Dc + kq * 64) * Hc + h;
    #pragma unroll 8
    for (int d = 0; d < 64; ++d)
        acc += qs[kq * 64 + d] * w[(size_t)d * Hc];
    red[kq][h] = acc;
    __syncthreads();

    if (t < 128)
        qb[bn * Hc + t] = b1[t] + red[0][t] + red[1][t] + red[2][t] + red[3][t];
}

// ---------------------------------------------------------------------------
// main: persistent block per bn. grid (256), 1024 thr (16 waves), 1 block/CU.
// 32x32x16 MFMA, operands SWAPPED: A = Mt (m=h, in registers, loaded once),
// B = att tile (n=a, ds_read_b128 from LDS). C/D: col=lane&31 -> a,
// row=(reg&3)+8*(reg>>2)+4*(lane>>5) -> h  => W2-reduction is in-lane over
// regs + ONE shfl_xor(32), killing the old 64-swizzle butterfly.
// Wave w: a-tile (w&3)*32, h-tile (w>>2)*32.
// ---------------------------------------------------------------------------
__global__ __launch_bounds__(1024, 4) void main_kernel(
    const float* __restrict__ att1, const int* __restrict__ tags,
    const unsigned short* __restrict__ Mt_hi, const unsigned short* __restrict__ Mt_lo,
    const float* __restrict__ qb, const float* __restrict__ W2,
    const float* __restrict__ b2, const void* __restrict__ tptr,
    float* __restrict__ out)
{
    __shared__ unsigned short A_s[2][128][136];  // ping-pong bf16 att tiles
    __shared__ float part2[128][5];              // [a][hg] logit partials
    __shared__ float part3[8][132];              // phase-3 partials
    __shared__ float e_s[128];
    __shared__ float2 qw_s[128];                 // {qb, w2}
    __shared__ float zfin[2];

    const int t    = threadIdx.x;
    const int wave = t >> 6;          // 0..15
    const int lane = t & 63;
    const int l31  = lane & 31;
    const int half = lane >> 5;
    const int ag   = wave & 3;        // a-group: a = ag*32 + l31
    const int hg   = wave >> 2;       // h-group: h-tile hg*32
    const int bn = blockIdx.x;
    const int b  = bn >> 2;

    const float* att_bn = att1 + (size_t)bn * Ac * Oc;

    // ---- prologue: tile-0 staging loads (HBM) ----
    f4 sv[4];
    #pragma unroll
    for (int s = 0; s < 4; s++) {
        int idx = t + 1024 * s;
        sv[s] = *(const f4*)(att_bn + (size_t)idx * 4);
    }

    // ---- A-operand fragments (Mt hi/lo), once per block ----
    // A[m][k]: m = lane&31 -> h = hg*32+l31 ; k = half*8+j -> o = ks*16+half*8+j
    const size_t arow = ((size_t)b * Hc + hg * 32 + l31) * Oc + half * 8;
    short8 Ah[8], Al[8];
    #pragma unroll
    for (int ks = 0; ks < 8; ks++) {
        Ah[ks] = *(const short8*)(Mt_hi + arow + ks * 16);
        Al[ks] = *(const short8*)(Mt_lo + arow + ks * 16);
    }

    if (t < 128) {
        float2 qw; qw.x = qb[bn * Hc + t]; qw.y = W2[t];
        qw_s[t] = qw;
    }
    int tg_cur = (t < 128) ? tags[(size_t)bn * Ac + t] : 0;
    const float b2v  = b2[0];
    const float tval = decode_t(tptr);

    float z_reg = 0.f, out_reg = 0.f;

    for (int tile = 0; tile < 8; ++tile) {
        const int buf = tile & 1;
        const float* tile_ptr = att_bn + (size_t)tile * 128 * Oc;

        // ---- convert staged fp32 -> bf16 RNE into LDS ----
        #pragma unroll
        for (int s = 0; s < 4; s++) {
            int idx = t + 1024 * s;
            int r = idx >> 5, c4 = idx & 31;
            us4 h4;
            #pragma unroll
            for (int j = 0; j < 4; j++) h4[j] = bf16_rne(sv[s][j]);
            *(us4*)&A_s[buf][r][c4 * 4] = h4;
        }
        __syncthreads();

        // ---- prefetch next tile (in flight through this tile's compute) ----
        int tg_next = 0;
        if (tile < 7) {
            const float* np = att_bn + (size_t)(tile + 1) * 128 * Oc;
            #pragma unroll
            for (int s = 0; s < 4; s++) {
                int idx = t + 1024 * s;
                sv[s] = *(const f4*)(np + (size_t)idx * 4);
            }
            if (t < 128) tg_next = tags[(size_t)bn * Ac + (tile + 1) * 128 + t];
        }

        // ---- MFMA: D[h][a] += Mt(hi+lo) x att_bf16 ----
        f32x16 acc = (f32x16)(0.f);
        #pragma unroll
        for (int ks = 0; ks < 8; ks++) {
            short8 bv = *(const short8*)&A_s[buf][ag * 32 + l31][ks * 16 + half * 8];
            acc = __builtin_amdgcn_mfma_f32_32x32x16_bf16(Ah[ks], bv, acc, 0, 0, 0);
            acc = __builtin_amdgcn_mfma_f32_32x32x16_bf16(Al[ks], bv, acc, 0, 0, 0);
        }

        // ---- epilogue: +qb, relu, *W2, in-lane sum over 16 h-rows ----
        float p = 0.f;
        #pragma unroll
        for (int reg = 0; reg < 16; reg++) {
            int h = hg * 32 + (reg & 3) + 8 * (reg >> 2) + 4 * half;
            float2 qw = qw_s[h];     // broadcast within half-wave
            float v = acc[reg] + qw.x;
            v = v > 0.f ? v : 0.f;
            p += v * qw.y;
        }
        p += __shfl_xor(p, 32);      // combine the two halves (32 h total)
        if (half == 0) part2[ag * 32 + l31][hg] = p;
        __syncthreads();

        // ---- masked exp; accumulate Z in registers ----
        if (t < 128) {
            float sum = part2[t][0] + part2[t][1] + part2[t][2] + part2[t][3] + b2v;
            float logit = sum / tval;
            float e = (tg_cur > 0) ? __expf(logit) : 0.f;
            e_s[t] = e;
            z_reg += e;
        }
        __syncthreads();

        // ---- phase 3: partial out[o] += sum_a e[a]*att1[a,o]  (L2-hot) ----
        {
            const int o = t & 127;
            const int g = t >> 7;   // 0..7, 16 rows each
            const float* ab = tile_ptr + (size_t)(g * 16) * Oc + o;
            float accum = 0.f;
            #pragma unroll
            for (int a = 0; a < 16; a++)
                accum += e_s[g * 16 + a] * ab[(size_t)a * Oc];
            part3[g][o] = accum;
        }
        __syncthreads();

        if (t < 128) {
            float s = 0.f;
            #pragma unroll
            for (int g = 0; g < 8; g++) s += part3[g][t];
            out_reg += s;
        }
        tg_cur = tg_next;
    }

    // ---- finalize: reduce Z across waves 0-1, write output ----
    __syncthreads();
    if (t < 128) {
        float z = z_reg;
        #pragma unroll
        for (int off = 32; off > 0; off >>= 1) z += __shfl_down(z, off);
        if (lane == 0) zfin[wave] = z;
    }
    __syncthreads();
    if (t < 128) {
        float Z = zfin[0] + zfin[1];
        out[(size_t)bn * Oc + t] = out_reg / Z;
    }
}

extern "C" void kernel_launch(void* const* d_in, const int* in_sizes, int n_in,
                              void* d_out, int out_size, void* d_ws, size_t ws_size,
                              hipStream_t stream)
{
    (void)in_sizes; (void)n_in; (void)out_size; (void)ws_size;

    const float* q    = (const float*)d_in[0];
    const float* att1 = (const float*)d_in[1];
    const float* obj  = (const float*)d_in[2];
    const int*   tags = (const int*)d_in[3];
    const float* W1   = (const float*)d_in[4];
    const float* b1   = (const float*)d_in[5];
    const float* W2   = (const float*)d_in[6];
    const float* b2   = (const float*)d_in[7];
    const void*  tptr = d_in[8];
    float* out = (float*)d_out;

    char* wsb = (char*)d_ws;
    unsigned short* Mt_hi = (unsigned short*)wsb;                          // 2 MB
    unsigned short* Mt_lo = (unsigned short*)(wsb + (size_t)2*1024*1024);  // 2 MB
    float* qbuf = (float*)(wsb + (size_t)4*1024*1024);   // BN*H floats

    prep_M_kernel<<<dim3(4, 2, Bc), 256, 0, stream>>>(obj, W1, Mt_hi, Mt_lo);
    prep_qb_kernel<<<dim3(BN), 512, 0, stream>>>(q, W1, b1, qbuf);
    main_kernel<<<dim3(BN), 1024, 0, stream>>>(att1, tags, Mt_hi, Mt_lo,
                                               qbuf, W2, b2, tptr, out);
}